// Round 12
// baseline (59.025 us; speedup 1.0000x reference)
//
#include <hip/hip_runtime.h>

#define HH 256
#define WW 256
#define CC 64
#define NG 8
#define NE 32
#define PX 32
#define THRESH 15.0f

typedef float f32x4 __attribute__((ext_vector_type(4)));

// out layout: feats (8,256,256,65) floats, then mask (8,256,256) floats
#define FEATS_ELEMS ((size_t)NG * HH * WW * 65)
// ws layout: S (256,256,64) pixel-major, wm (8,256,256), wp (8,256,256)
#define S_ELEMS  ((size_t)HH * WW * CC)
#define MP_ELEMS ((size_t)NG * HH * WW)
#define WS_NEEDED ((S_ELEMS + 2 * MP_ELEMS) * sizeof(float) + 64)

#define IMG_ELEMS (CC * 2 * 33)   // 4224 staged elements

// ================= K1: sample S + mask/pinfo -> ws, mask -> out =================
__global__ __launch_bounds__(256, 6) void k1_sample_mask(
    const float* __restrict__ img,    // (64,256,256)
    const float* __restrict__ edges,  // (8,32,4)
    float* __restrict__ out,
    float* __restrict__ S,
    float* __restrict__ wm,
    float* __restrict__ wp)
{
#pragma clang fp contract(off)
    __shared__ __align__(16) float s_buf[66 * 65];   // img tile [(yy*33+x)*65 + c]
    __shared__ float4 s_k1[NG * NE];                 // e0v, e0u, dn0, dn1
    __shared__ float2 s_k2[NG * NE];                 // e1v, e1u
    __shared__ float  s_k3[NG * NE];                 // Lm

    const int tid  = threadIdx.x;
    const int wv   = tid >> 6;
    const int lane = tid & 63;
    const int u0   = blockIdx.x * PX;
    const int v    = blockIdx.y;

    // Phase A: per-edge precompute
    {
        const float4 e4 = reinterpret_cast<const float4*>(edges)[tid];
        const float e0v = e4.x * 256.0f;
        const float e0u = e4.y * 256.0f;
        const float e1v = e4.z * 256.0f;
        const float e1u = e4.w * 256.0f;
        const float d0 = e1v - e0v;
        const float d1 = e1u - e0u;
        const float L  = __fsqrt_rn(d0 * d0 + d1 * d1);
        const float Lm = fmaxf(L, 1e-4f);
        s_k1[tid] = make_float4(e0v, e0u, __fdiv_rn(d0, Lm), __fdiv_rn(d1, Lm));
        s_k2[tid] = make_float2(e1v, e1u);
        s_k3[tid] = Lm;
    }
    __syncthreads();

    // Phase C-issue: img tile loads into registers (in flight during Phase B)
    float cbuf[17];
    #pragma unroll
    for (int t = 0; t < 17; ++t) {
        const int i = tid + t * 256;
        float val = 0.0f;
        if (i < IMG_ELEMS) {
            const int c  = i / 66;
            const int r  = i - c * 66;
            const int yy = r / 33;
            const int x  = r - yy * 33;
            const int gy = v - 1 + yy;
            const int gx = u0 - 1 + x;
            if (gy >= 0 && gx >= 0) {        // gy<=255, gx<=255 always
                val = img[((size_t)c * HH + gy) * WW + gx];
            }
        }
        cbuf[t] = val;
    }

    // Phase B: mask + pinfo -> ws (+ mask output); overlaps load latency
    {
        const int px = tid & (PX - 1);
        const int g  = tid >> 5;
        const float U = (float)(u0 + px);
        const float V = (float)v;
        float sm = 0.0f, cnt = 0.0f;
        bool any = false;
        for (int e = 0; e < NE; ++e) {
            const int idx = g * NE + e;
            const float4 k1 = s_k1[idx];
            const float2 k2 = s_k2[idx];
            const float  Lm = s_k3[idx];
            const float diff0 = V - k1.x;
            const float diff1 = U - k1.y;
            const float ndv = diff0 * k1.w - diff1 * k1.z;
            const float ddn = diff0 * k1.z + diff1 * k1.w;
            const float dd  = __fdiv_rn(ddn, Lm);
            const float r0sq = diff0 * diff0 + diff1 * diff1;
            const float f0 = V - k2.x;
            const float f1 = U - k2.y;
            const float r1sq = f0 * f0 + f1 * f1;
            const bool m = ((fabsf(ndv) <= THRESH) && (dd <= 1.0f) && (dd >= 0.0f))
                           || (r0sq <= 225.0f) || (r1sq <= 225.0f);
            if (m) {
                any = true;
                sm += fminf(dd, 1.0f - dd);
                cnt += 1.0f;
            }
        }
        const float pf = __fdiv_rn(sm, fmaxf(cnt, 1e-4f));
        const float mv = any ? 1.0f : 0.0f;
        const size_t o = ((size_t)g * HH + v) * WW + (u0 + px);
        wm[o] = mv;
        wp[o] = pf;
        out[FEATS_ELEMS + o] = mv;
    }

    // Phase C-commit: registers -> LDS img tile
    #pragma unroll
    for (int t = 0; t < 17; ++t) {
        const int i = tid + t * 256;
        if (i < IMG_ELEMS) {
            const int c  = i / 66;
            const int r  = i - c * 66;
            const int yy = r / 33;
            const int x  = r - yy * 33;
            s_buf[(yy * 33 + x) * 65 + c] = cbuf[t];
        }
    }
    __syncthreads();

    // Phase D: 2x2 box sample; wave wv owns pixels [8wv,8wv+8), lane = channel.
    // Store S pixel-major (coalesced 256B per wave-instr). NOT nontemporal (K2 reads it).
    #pragma unroll
    for (int i = 0; i < 8; ++i) {
        const int p = wv * 8 + i;
        const float s = s_buf[(p) * 65 + lane] * 0.25f
                      + s_buf[(p + 1) * 65 + lane] * 0.25f
                      + s_buf[(33 + p) * 65 + lane] * 0.25f
                      + s_buf[(34 + p) * 65 + lane] * 0.25f;
        S[((size_t)v * WW + u0 + p) * CC + lane] = s;
    }
}

// ================= K2: LDS-staged feats streamer (full occupancy) =================
__global__ __launch_bounds__(256, 8) void k2_stream(
    const float* __restrict__ S,
    const float* __restrict__ wm,
    const float* __restrict__ wp,
    float* __restrict__ out)
{
    __shared__ __align__(16) float s_S[PX * CC + 8];   // 2048 + pad (s0+3 can touch 2048)
    __shared__ __align__(16) float s_m[NG * PX];
    __shared__ __align__(16) float s_p[NG * PX];

    const int tid = threadIdx.x;
    const int u0  = blockIdx.x * PX;
    const int v   = blockIdx.y;

    // stage S tile: 2048 floats = 512 f32x4, coalesced
    {
        const f32x4* src = reinterpret_cast<const f32x4*>(&S[((size_t)v * WW + u0) * CC]);
        f32x4* dst = reinterpret_cast<f32x4*>(s_S);
        dst[tid]       = src[tid];
        dst[tid + 256] = src[tid + 256];
    }
    // stage m/p: 8g x 32px each, f32x4 (u0 % 32 == 0 -> 16B aligned)
    if (tid < 64) {
        const int g = tid >> 3, j = tid & 7;
        *reinterpret_cast<f32x4*>(&s_m[g * PX + 4 * j]) =
            *reinterpret_cast<const f32x4*>(&wm[((size_t)g * HH + v) * WW + u0 + 4 * j]);
    } else if (tid < 128) {
        const int t2 = tid - 64;
        const int g = t2 >> 3, j = t2 & 7;
        *reinterpret_cast<f32x4*>(&s_p[g * PX + 4 * j]) =
            *reinterpret_cast<const f32x4*>(&wp[((size_t)g * HH + v) * WW + u0 + 4 * j]);
    }
    __syncthreads();

    // hoisted g-invariant per-thread quad params + S values
    int  e_f[3], e_p0[3], e_b[3];
    bool e_on[3];
    float ev0[3], ev1[3], ev2[3], ev3[3];
    #pragma unroll
    for (int k = 0; k < 3; ++k) {
        const int q = tid + k * 256;
        e_on[k] = (q < 520);
        const int f  = q * 4;
        const int p0 = (int)((unsigned)f / 65u);
        e_f[k] = f; e_p0[k] = p0; e_b[k] = (p0 + 1) * 65 - f;
        const int s0 = f - p0;                 // S index of out[f] (if not pinfo)
        if (e_on[k]) {
            ev0[k] = s_S[s0];
            ev1[k] = s_S[s0 + 1];
            ev2[k] = s_S[s0 + 2];
            ev3[k] = s_S[s0 + 3];
        }
    }

    for (int g = 0; g < NG; ++g) {
        float* gout = out + (((size_t)g * HH + v) * WW + u0) * 65;
        const float* mg = &s_m[g * PX];
        const float* pg = &s_p[g * PX];
        #pragma unroll
        for (int k = 0; k < 3; ++k) {
            if (e_on[k]) {
                const int f  = e_f[k];
                const int p0 = e_p0[k];
                const int b  = e_b[k];
                const float v0 = ev0[k], v1 = ev1[k], v2 = ev2[k], v3 = ev3[k];
                const float m0 = mg[p0];
                const float m1 = mg[(b < 4) ? (p0 + 1) : p0];
                const float pi = pg[p0];
                // out[f+j]: j==b-1 -> pinfo; j<b-1 -> vec[j]; j>=b -> vec[j-1]
                f32x4 r;
                r.x = ((b == 1) ? pi : v0) * ((0 < b) ? m0 : m1);
                r.y = ((b == 2) ? pi : ((b == 1) ? v0 : v1)) * ((1 < b) ? m0 : m1);
                r.z = ((b == 3) ? pi : ((b <= 2) ? v1 : v2)) * ((2 < b) ? m0 : m1);
                r.w = ((b == 4) ? pi : ((b <= 3) ? v2 : v3)) * ((3 < b) ? m0 : m1);
                __builtin_nontemporal_store(r, reinterpret_cast<f32x4*>(&gout[f]));
            }
        }
    }
}

// ================= Fallback: R6 fused kernel (proven 40.4us) =================
__global__ __launch_bounds__(256, 6) void fused_sparse_encoder(
    const float* __restrict__ img,
    const float* __restrict__ edges,
    float* __restrict__ out)
{
#pragma clang fp contract(off)
    __shared__ __align__(16) float s_buf[66 * 65];
    __shared__ float4 s_k1[NG * NE];
    __shared__ float2 s_k2[NG * NE];
    __shared__ float  s_k3[NG * NE];
    __shared__ float  s_m[NG * PX];
    __shared__ float  s_p[NG * PX];

    const int tid  = threadIdx.x;
    const int wv   = tid >> 6;
    const int lane = tid & 63;
    const int u0   = blockIdx.x * PX;
    const int v    = blockIdx.y;

    {
        const float4 e4 = reinterpret_cast<const float4*>(edges)[tid];
        const float e0v = e4.x * 256.0f;
        const float e0u = e4.y * 256.0f;
        const float e1v = e4.z * 256.0f;
        const float e1u = e4.w * 256.0f;
        const float d0 = e1v - e0v;
        const float d1 = e1u - e0u;
        const float L  = __fsqrt_rn(d0 * d0 + d1 * d1);
        const float Lm = fmaxf(L, 1e-4f);
        s_k1[tid] = make_float4(e0v, e0u, __fdiv_rn(d0, Lm), __fdiv_rn(d1, Lm));
        s_k2[tid] = make_float2(e1v, e1u);
        s_k3[tid] = Lm;
    }
    __syncthreads();

    float cbuf[17];
    #pragma unroll
    for (int t = 0; t < 17; ++t) {
        const int i = tid + t * 256;
        float val = 0.0f;
        if (i < IMG_ELEMS) {
            const int c  = i / 66;
            const int r  = i - c * 66;
            const int yy = r / 33;
            const int x  = r - yy * 33;
            const int gy = v - 1 + yy;
            const int gx = u0 - 1 + x;
            if (gy >= 0 && gx >= 0) val = img[((size_t)c * HH + gy) * WW + gx];
        }
        cbuf[t] = val;
    }

    {
        const int px = tid & (PX - 1);
        const int g  = tid >> 5;
        const float U = (float)(u0 + px);
        const float V = (float)v;
        float sm = 0.0f, cnt = 0.0f;
        bool any = false;
        for (int e = 0; e < NE; ++e) {
            const int idx = g * NE + e;
            const float4 k1 = s_k1[idx];
            const float2 k2 = s_k2[idx];
            const float  Lm = s_k3[idx];
            const float diff0 = V - k1.x;
            const float diff1 = U - k1.y;
            const float ndv = diff0 * k1.w - diff1 * k1.z;
            const float ddn = diff0 * k1.z + diff1 * k1.w;
            const float dd  = __fdiv_rn(ddn, Lm);
            const float r0sq = diff0 * diff0 + diff1 * diff1;
            const float f0 = V - k2.x;
            const float f1 = U - k2.y;
            const float r1sq = f0 * f0 + f1 * f1;
            const bool m = ((fabsf(ndv) <= THRESH) && (dd <= 1.0f) && (dd >= 0.0f))
                           || (r0sq <= 225.0f) || (r1sq <= 225.0f);
            if (m) { any = true; sm += fminf(dd, 1.0f - dd); cnt += 1.0f; }
        }
        const float pf = __fdiv_rn(sm, fmaxf(cnt, 1e-4f));
        const float mv = any ? 1.0f : 0.0f;
        s_m[g * PX + px] = mv;
        s_p[g * PX + px] = pf;
        out[FEATS_ELEMS + ((size_t)g * HH + v) * WW + (u0 + px)] = mv;
    }

    #pragma unroll
    for (int t = 0; t < 17; ++t) {
        const int i = tid + t * 256;
        if (i < IMG_ELEMS) {
            const int c  = i / 66;
            const int r  = i - c * 66;
            const int yy = r / 33;
            const int x  = r - yy * 33;
            s_buf[(yy * 33 + x) * 65 + c] = cbuf[t];
        }
    }
    __syncthreads();

    float sreg[8];
    #pragma unroll
    for (int i = 0; i < 8; ++i) {
        const int p = wv * 8 + i;
        sreg[i] = s_buf[(p) * 65 + lane] * 0.25f
                + s_buf[(p + 1) * 65 + lane] * 0.25f
                + s_buf[(33 + p) * 65 + lane] * 0.25f
                + s_buf[(34 + p) * 65 + lane] * 0.25f;
    }
    __syncthreads();
    #pragma unroll
    for (int i = 0; i < 8; ++i) {
        s_buf[(wv * 8 + i) * 65 + lane] = sreg[i];
    }
    __syncthreads();

    for (int g = 0; g < NG; ++g) {
        const float* msk = &s_m[g * PX];
        const float* pin = &s_p[g * PX];
        float* gout = out + (((size_t)g * HH + v) * WW + u0) * 65;
        #pragma unroll
        for (int k = 0; k < 3; ++k) {
            const int q = tid + k * 256;
            if (q < 520) {
                const int f  = q * 4;
                const int p0 = (int)((unsigned)f / 65u);
                const int b  = (p0 + 1) * 65 - f;
                const float4 tv = *reinterpret_cast<const float4*>(&s_buf[f]);
                const float m0 = msk[p0];
                const float m1 = msk[(b < 4) ? (p0 + 1) : p0];
                const float pi = pin[p0];
                f32x4 r;
                r.x = ((b == 1) ? pi : tv.x) * ((0 < b) ? m0 : m1);
                r.y = ((b == 2) ? pi : tv.y) * ((1 < b) ? m0 : m1);
                r.z = ((b == 3) ? pi : tv.z) * ((2 < b) ? m0 : m1);
                r.w = ((b == 4) ? pi : tv.w) * ((3 < b) ? m0 : m1);
                __builtin_nontemporal_store(r, reinterpret_cast<f32x4*>(&gout[f]));
            }
        }
    }
}

extern "C" void kernel_launch(void* const* d_in, const int* in_sizes, int n_in,
                              void* d_out, int out_size, void* d_ws, size_t ws_size,
                              hipStream_t stream) {
    const float* img   = (const float*)d_in[0];
    const float* edges = (const float*)d_in[1];
    float* out = (float*)d_out;

    if (ws_size >= WS_NEEDED) {
        float* S  = (float*)d_ws;
        float* wm = S + S_ELEMS;
        float* wp = wm + MP_ELEMS;
        dim3 g1(WW / PX, HH);
        k1_sample_mask<<<g1, 256, 0, stream>>>(img, edges, out, S, wm, wp);
        dim3 g2(WW / PX, HH);
        k2_stream<<<g2, 256, 0, stream>>>(S, wm, wp, out);
    } else {
        dim3 grid(WW / PX, HH);
        fused_sparse_encoder<<<grid, 256, 0, stream>>>(img, edges, out);
    }
}

// Round 13
// 52.004 us; speedup vs baseline: 1.1350x; 1.1350x over previous
//
#include <hip/hip_runtime.h>

#define HH 256
#define WW 256
#define CC 64
#define NG 8
#define NE 32
#define PX 32           // pixels per block
#define THRESH 15.0f

typedef float f32x4 __attribute__((ext_vector_type(4)));

// out layout: feats (8,256,256,65) floats, then mask (8,256,256) floats
#define FEATS_ELEMS ((size_t)NG * HH * WW * 65)

// img tile in LDS (stride 64): row r = yy*33 + x ; yy in {0,1} -> img rows v-1,v ;
// x in [0,33) -> cols u0-1..u0+31 ; addr = r*64 + c ; 66*64 = 4224 floats (16.9 KB).
// t tile aliases rows 0..31: t(p,c) = p*64 + c (pure samples, stride 64 -- pinfo
// is composed in registers during Phase E via the validated R12-K2 select logic).
#define IMG_ELEMS (CC * 2 * 33)   // 4224 loaded elements

__global__ __launch_bounds__(256, 7) void fused_sparse_encoder(
    const float* __restrict__ img,    // (64,256,256)
    const float* __restrict__ edges,  // (8,32,4)
    float* __restrict__ out)
{
#pragma clang fp contract(off)
    __shared__ __align__(16) float s_buf[66 * 64];   // 16.9 KB, img tile then t tile
    __shared__ __align__(16) float4 s_e[NG * NE];    // raw edges*1 (4 KB)
    __shared__ float s_m[NG * PX];                   // 1 KB
    __shared__ float s_p[NG * PX];                   // 1 KB
    // total 22.9 KB -> 7 blocks/CU

    const int tid  = threadIdx.x;
    const int wv   = tid >> 6;
    const int lane = tid & 63;
    const int u0   = blockIdx.x * PX;
    const int v    = blockIdx.y;

    // ---- Phase A: stage raw edges (constants recomputed exactly per use)
    s_e[tid] = reinterpret_cast<const float4*>(edges)[tid];
    __syncthreads();

    // ---- Phase C-issue: img tile loads into registers (in flight during Phase B)
    float cbuf[17];
    #pragma unroll
    for (int t = 0; t < 17; ++t) {
        const int i = tid + t * 256;
        float val = 0.0f;
        if (i < IMG_ELEMS) {
            const int c  = i / 66;
            const int r  = i - c * 66;
            const int yy = r / 33;
            const int x  = r - yy * 33;
            const int gy = v - 1 + yy;
            const int gx = u0 - 1 + x;
            if (gy >= 0 && gx >= 0) {        // gy<=255, gx<=255 always
                val = img[((size_t)c * HH + gy) * WW + gx];
            }
        }
        cbuf[t] = val;
    }

    // ---- Phase B: mask + pinfo, one (g,px) per thread (overlaps load latency).
    //      Edge params recomputed per iteration in the EXACT reference op order.
    {
        const int px = tid & (PX - 1);
        const int g  = tid >> 5;
        const float U = (float)(u0 + px);
        const float V = (float)v;
        float sm = 0.0f, cnt = 0.0f;
        bool any = false;
        for (int e = 0; e < NE; ++e) {
            const float4 e4 = s_e[g * NE + e];
            const float e0v = e4.x * 256.0f;
            const float e0u = e4.y * 256.0f;
            const float e1v = e4.z * 256.0f;
            const float e1u = e4.w * 256.0f;
            const float d0 = e1v - e0v;
            const float d1 = e1u - e0u;
            const float L  = __fsqrt_rn(d0 * d0 + d1 * d1);
            const float Lm = fmaxf(L, 1e-4f);
            const float dn0 = __fdiv_rn(d0, Lm);
            const float dn1 = __fdiv_rn(d1, Lm);
            const float diff0 = V - e0v;
            const float diff1 = U - e0u;
            const float ndv = diff0 * dn1 - diff1 * dn0;
            const float ddn = diff0 * dn0 + diff1 * dn1;
            const float dd  = __fdiv_rn(ddn, Lm);
            const float r0sq = diff0 * diff0 + diff1 * diff1;
            const float f0 = V - e1v;
            const float f1 = U - e1u;
            const float r1sq = f0 * f0 + f1 * f1;
            const bool m = ((fabsf(ndv) <= THRESH) && (dd <= 1.0f) && (dd >= 0.0f))
                           || (r0sq <= 225.0f) || (r1sq <= 225.0f);
            if (m) {
                any = true;
                sm += fminf(dd, 1.0f - dd);
                cnt += 1.0f;
            }
        }
        const float pf = __fdiv_rn(sm, fmaxf(cnt, 1e-4f));
        const float mv = any ? 1.0f : 0.0f;
        s_m[g * PX + px] = mv;
        s_p[g * PX + px] = pf;
        out[FEATS_ELEMS + ((size_t)g * HH + v) * WW + (u0 + px)] = mv;
    }

    // ---- Phase C-commit: registers -> LDS img tile (stride 64)
    #pragma unroll
    for (int t = 0; t < 17; ++t) {
        const int i = tid + t * 256;
        if (i < IMG_ELEMS) {
            const int c  = i / 66;
            const int r  = i - c * 66;
            const int yy = r / 33;
            const int x  = r - yy * 33;
            s_buf[(yy * 33 + x) * 64 + c] = cbuf[t];
        }
    }
    __syncthreads();   // barrier 1: tile + s_m/s_p visible

    // ---- Phase D1: 2x2 box sample; wave wv owns pixels [8wv, 8wv+8), lane = channel
    float sreg[8];
    #pragma unroll
    for (int i = 0; i < 8; ++i) {
        const int p = wv * 8 + i;
        sreg[i] = s_buf[(p) * 64 + lane] * 0.25f
                + s_buf[(p + 1) * 64 + lane] * 0.25f
                + s_buf[(33 + p) * 64 + lane] * 0.25f
                + s_buf[(34 + p) * 64 + lane] * 0.25f;
    }
    __syncthreads();   // barrier 2: all samples read before t overwrites img rows

    // ---- Phase D2: transpose into t region (rows 0..31 of s_buf, stride 64)
    #pragma unroll
    for (int i = 0; i < 8; ++i) {
        s_buf[(wv * 8 + i) * 64 + lane] = sreg[i];
    }
    __syncthreads();   // barrier 3: t tile complete

    // ---- Phase E: hoisted g-invariant per-thread quad params + t reads (stride-64
    //      select logic identical to validated R12-K2), then 8 store passes.
    int  e_p0[3], e_b[3], e_fq[3];
    bool e_on[3];
    float ev0[3], ev1[3], ev2[3], ev3[3];
    #pragma unroll
    for (int k = 0; k < 3; ++k) {
        const int q = tid + k * 256;
        e_on[k] = (q < 520);
        const int f  = q * 4;
        const int p0 = (int)((unsigned)f / 65u);
        e_fq[k] = f; e_p0[k] = p0; e_b[k] = (p0 + 1) * 65 - f;
        const int s0 = f - p0;               // t index of out[f] (if not pinfo)
        if (e_on[k]) {
            ev0[k] = s_buf[s0];
            ev1[k] = s_buf[s0 + 1];
            ev2[k] = s_buf[s0 + 2];
            ev3[k] = (s0 + 3 < 2048) ? s_buf[s0 + 3] : 0.0f;   // only unused slot can exceed
        }
    }

    for (int g = 0; g < NG; ++g) {
        float* gout = out + (((size_t)g * HH + v) * WW + u0) * 65;
        const float* mg = &s_m[g * PX];
        const float* pg = &s_p[g * PX];
        #pragma unroll
        for (int k = 0; k < 3; ++k) {
            if (e_on[k]) {
                const int f  = e_fq[k];
                const int p0 = e_p0[k];
                const int b  = e_b[k];
                const float v0 = ev0[k], v1 = ev1[k], v2 = ev2[k], v3 = ev3[k];
                const float m0 = mg[p0];
                const float m1 = mg[(b < 4) ? (p0 + 1) : p0];
                const float pi = pg[p0];
                // out[f+j]: j==b-1 -> pinfo; j<b-1 -> vec[j]; j>=b -> vec[j-1]
                f32x4 r;
                r.x = ((b == 1) ? pi : v0) * ((0 < b) ? m0 : m1);
                r.y = ((b == 2) ? pi : ((b == 1) ? v0 : v1)) * ((1 < b) ? m0 : m1);
                r.z = ((b == 3) ? pi : ((b <= 2) ? v1 : v2)) * ((2 < b) ? m0 : m1);
                r.w = ((b == 4) ? pi : ((b <= 3) ? v2 : v3)) * ((3 < b) ? m0 : m1);
                __builtin_nontemporal_store(r, reinterpret_cast<f32x4*>(&gout[f]));
            }
        }
    }
}

extern "C" void kernel_launch(void* const* d_in, const int* in_sizes, int n_in,
                              void* d_out, int out_size, void* d_ws, size_t ws_size,
                              hipStream_t stream) {
    const float* img   = (const float*)d_in[0];
    const float* edges = (const float*)d_in[1];
    float* out = (float*)d_out;
    dim3 grid(WW / PX, HH);
    fused_sparse_encoder<<<grid, 256, 0, stream>>>(img, edges, out);
}

// Round 14
// 49.137 us; speedup vs baseline: 1.2012x; 1.0583x over previous
//
#include <hip/hip_runtime.h>
#include <hip/hip_fp16.h>

#define HH 256
#define WW 256
#define CC 64
#define NG 8
#define NE 32
#define PX 32           // pixels per block
#define THRESH 15.0f

typedef float f32x4 __attribute__((ext_vector_type(4)));

// out layout: feats (8,256,256,65) floats, then mask (8,256,256) floats
#define FEATS_ELEMS ((size_t)NG * HH * WW * 65)

// img tile in LDS (stride 65 = conflict-free for commit/read): row r = yy*33 + x ;
// yy in {0,1} -> img rows v-1,v ; x in [0,33) -> cols u0-1..u0+31 ; addr = r*65 + c.
// 66*65 = 4290 floats (17.16 KB). t tile aliases rows 0..31: t(p,c) = p*65 + c.
#define IMG_ELEMS (CC * 2 * 33)   // 4224 loaded elements

__global__ __launch_bounds__(256, 7) void fused_sparse_encoder(
    const float* __restrict__ img,    // (64,256,256)
    const float* __restrict__ edges,  // (8,32,4)
    float* __restrict__ out)
{
#pragma clang fp contract(off)
    __shared__ __align__(16) float  s_buf[66 * 65];   // 17160 B
    __shared__ __align__(16) float4 s_e[NG * NE];     //  4096 B raw edges
    __shared__ float  s_m[NG * PX];                   //  1024 B mask (fp32)
    __shared__ __half s_p[NG * PX];                   //   512 B pinfo (half)
    // total 22.8 KB -> 7 blocks/CU

    const int tid  = threadIdx.x;
    const int wv   = tid >> 6;
    const int lane = tid & 63;
    const int u0   = blockIdx.x * PX;
    const int v    = blockIdx.y;

    // ---- Phase A: stage raw edges
    s_e[tid] = reinterpret_cast<const float4*>(edges)[tid];
    __syncthreads();

    // ---- Phase C-issue: img tile loads into registers (in flight during Phase B)
    float cbuf[17];
    #pragma unroll
    for (int t = 0; t < 17; ++t) {
        const int i = tid + t * 256;
        float val = 0.0f;
        if (i < IMG_ELEMS) {
            const int c  = i / 66;
            const int r  = i - c * 66;
            const int yy = r / 33;
            const int x  = r - yy * 33;
            const int gy = v - 1 + yy;
            const int gx = u0 - 1 + x;
            if (gy >= 0 && gx >= 0) {        // gy<=255, gx<=255 always
                val = img[((size_t)c * HH + gy) * WW + gx];
            }
        }
        cbuf[t] = val;
    }

    // ---- Phase B: mask + pinfo, one (g,px) per thread; edge params recomputed
    //      per iteration in the EXACT reference op order (bit-identical).
    {
        const int px = tid & (PX - 1);
        const int g  = tid >> 5;
        const float U = (float)(u0 + px);
        const float V = (float)v;
        float sm = 0.0f, cnt = 0.0f;
        bool any = false;
        for (int e = 0; e < NE; ++e) {
            const float4 e4 = s_e[g * NE + e];
            const float e0v = e4.x * 256.0f;
            const float e0u = e4.y * 256.0f;
            const float e1v = e4.z * 256.0f;
            const float e1u = e4.w * 256.0f;
            const float d0 = e1v - e0v;
            const float d1 = e1u - e0u;
            const float L  = __fsqrt_rn(d0 * d0 + d1 * d1);
            const float Lm = fmaxf(L, 1e-4f);
            const float dn0 = __fdiv_rn(d0, Lm);
            const float dn1 = __fdiv_rn(d1, Lm);
            const float diff0 = V - e0v;
            const float diff1 = U - e0u;
            const float ndv = diff0 * dn1 - diff1 * dn0;
            const float ddn = diff0 * dn0 + diff1 * dn1;
            const float dd  = __fdiv_rn(ddn, Lm);
            const float r0sq = diff0 * diff0 + diff1 * diff1;
            const float f0 = V - e1v;
            const float f1 = U - e1u;
            const float r1sq = f0 * f0 + f1 * f1;
            const bool m = ((fabsf(ndv) <= THRESH) && (dd <= 1.0f) && (dd >= 0.0f))
                           || (r0sq <= 225.0f) || (r1sq <= 225.0f);
            if (m) {
                any = true;
                sm += fminf(dd, 1.0f - dd);
                cnt += 1.0f;
            }
        }
        const float pf = __fdiv_rn(sm, fmaxf(cnt, 1e-4f));
        const float mv = any ? 1.0f : 0.0f;
        s_m[g * PX + px] = mv;
        s_p[g * PX + px] = __float2half(pf);
        out[FEATS_ELEMS + ((size_t)g * HH + v) * WW + (u0 + px)] = mv;
    }

    // ---- Phase C-commit: registers -> LDS img tile (stride 65, conflict-free)
    #pragma unroll
    for (int t = 0; t < 17; ++t) {
        const int i = tid + t * 256;
        if (i < IMG_ELEMS) {
            const int c  = i / 66;
            const int r  = i - c * 66;
            const int yy = r / 33;
            const int x  = r - yy * 33;
            s_buf[(yy * 33 + x) * 65 + c] = cbuf[t];
        }
    }
    __syncthreads();   // barrier 1: tile + s_m/s_p visible

    // ---- Phase D1: 2x2 box sample; wave wv owns pixels [8wv, 8wv+8), lane = channel
    float sreg[8];
    #pragma unroll
    for (int i = 0; i < 8; ++i) {
        const int p = wv * 8 + i;
        sreg[i] = s_buf[(p) * 65 + lane] * 0.25f
                + s_buf[(p + 1) * 65 + lane] * 0.25f
                + s_buf[(33 + p) * 65 + lane] * 0.25f
                + s_buf[(34 + p) * 65 + lane] * 0.25f;
    }
    __syncthreads();   // barrier 2: all samples read before t overwrites img rows

    // ---- Phase D2: transpose into t region (rows 0..31 of s_buf, stride 65)
    #pragma unroll
    for (int i = 0; i < 8; ++i) {
        s_buf[(wv * 8 + i) * 65 + lane] = sreg[i];
    }
    __syncthreads();   // barrier 3: t tile complete

    // ---- Phase E: hoisted g-invariant per-thread quad params + b128 t reads,
    //      then 8 aligned nontemporal store passes.
    int  e_f[3], e_p0[3], e_b[3];
    bool e_on[3];
    f32x4 e_tv[3];
    #pragma unroll
    for (int k = 0; k < 3; ++k) {
        const int q = tid + k * 256;
        e_on[k] = (q < 520);
        const int f  = q * 4;
        const int p0 = (int)((unsigned)f / 65u);
        e_f[k] = f; e_p0[k] = p0; e_b[k] = (p0 + 1) * 65 - f;
        if (e_on[k]) e_tv[k] = *reinterpret_cast<const f32x4*>(&s_buf[f]);
    }

    for (int g = 0; g < NG; ++g) {
        float* gout = out + (((size_t)g * HH + v) * WW + u0) * 65;
        const float* mg = &s_m[g * PX];
        const __half* pg = &s_p[g * PX];
        #pragma unroll
        for (int k = 0; k < 3; ++k) {
            if (e_on[k]) {
                const int f  = e_f[k];
                const int p0 = e_p0[k];
                const int b  = e_b[k];
                const f32x4 tv = e_tv[k];
                const float m0 = mg[p0];
                const float m1 = mg[(b < 4) ? (p0 + 1) : p0];
                const float pi = __half2float(pg[p0]);
                f32x4 r;
                r.x = ((b == 1) ? pi : tv.x) * ((0 < b) ? m0 : m1);
                r.y = ((b == 2) ? pi : tv.y) * ((1 < b) ? m0 : m1);
                r.z = ((b == 3) ? pi : tv.z) * ((2 < b) ? m0 : m1);
                r.w = ((b == 4) ? pi : tv.w) * ((3 < b) ? m0 : m1);
                __builtin_nontemporal_store(r, reinterpret_cast<f32x4*>(&gout[f]));
            }
        }
    }
}

extern "C" void kernel_launch(void* const* d_in, const int* in_sizes, int n_in,
                              void* d_out, int out_size, void* d_ws, size_t ws_size,
                              hipStream_t stream) {
    const float* img   = (const float*)d_in[0];
    const float* edges = (const float*)d_in[1];
    float* out = (float*)d_out;
    dim3 grid(WW / PX, HH);
    fused_sparse_encoder<<<grid, 256, 0, stream>>>(img, edges, out);
}